// Round 6
// baseline (207.417 us; speedup 1.0000x reference)
//
#include <hip/hip_runtime.h>

#define Nn 8192
#define Bb 4
#define KK 20
#define OO 64
#define EPSF 1e-5f
#define SLOPEF 0.2f

#define NBUCK 56
#define CAP 96                // E[C]~50 with subset-P1; exact fallback covers tails
#define BOFF 476              // (bits(2^-8) >> 21)
#define CLO 0.00390625f       // 2^-8
#define CHI 63.9999961853f    // 0x427FFFFF, largest float < 64 -> bucket <= 55
#define SEG 512               // points per wave (16 waves x 512 = 8192)
#define SUB 256               // P1 subset per wave (first half of segment) -> exact lower bound

// ---------------- u/v/P precompute (pack fused in; lane o==0 writes P) ----------------------

__global__ __launch_bounds__(256) void uv_kernel(const float* __restrict__ x,
                                                 const float* __restrict__ W,
                                                 float* __restrict__ u,
                                                 float* __restrict__ v,
                                                 float4* __restrict__ P) {
  int gid = blockIdx.x * 256 + threadIdx.x;
  int o  = gid & 63;
  int bn = gid >> 6;
  int b  = bn >> 13;
  int n  = bn & (Nn - 1);
  const float* xb = x + b * 3 * Nn;
  float x0 = xb[n], x1 = xb[Nn + n], x2 = xb[2 * Nn + n];   // wave-uniform -> scalar loads
  if (o == 0) P[bn] = make_float4(x0, x1, x2, x0 * x0 + x1 * x1 + x2 * x2);
  float wa0 = W[o * 6 + 0], wa1 = W[o * 6 + 1], wa2 = W[o * 6 + 2];
  float wb0 = W[o * 6 + 3], wb1 = W[o * 6 + 4], wb2 = W[o * 6 + 5];
  u[gid] = (wa0 - wb0) * x0 + (wa1 - wb1) * x1 + (wa2 - wb2) * x2;
  v[gid] = wb0 * x0 + wb1 * x1 + wb2 * x2;
}

// ---------------- KNN via exact histogram-select (top-20 incl. self) ------------------------
// 1024 threads = 16 waves; wave w scans pts [w*512, (w+1)*512) for the same 64 rows
// (lane = row). P1 histograms only the first 256/wave (subset lower bound keeps exactness:
// >=20 subset points below T  =>  >=20 global points below T). P2 collects raw d < Tup.
// Any anomaly (cnt<20 from clamp edges, or cnt>CAP overflow) -> exact brute-force fallback,
// so the kernel is unconditionally exact and deterministic.

__global__ __launch_bounds__(1024, 8) void knn_kernel(const float4* __restrict__ P,
                                                      int* __restrict__ idx_out) {
  __shared__ unsigned long long cdk[CAP * 64];   // [c][lane]  49152 B
  __shared__ unsigned hist[NBUCK * 64];          // [bk][lane] 14336 B
  __shared__ unsigned ccnt[64];

  const int lane = threadIdx.x & 63;
  const int wid  = __builtin_amdgcn_readfirstlane(threadIdx.x >> 6);
  const int b    = blockIdx.y;
  const int n    = blockIdx.x * 64 + lane;

  for (int t = threadIdx.x; t < NBUCK * 64; t += 1024) hist[t] = 0u;
  if (threadIdx.x < 64) ccnt[threadIdx.x] = 0u;

  const float4* __restrict__ Pb  = P + b * Nn;
  const float4* __restrict__ seg = Pb + wid * SEG;   // wave-uniform base -> scalar loads
  const float4 me = Pb[n];

  unsigned* hrow0 = &hist[lane] - (BOFF << 6);

  __syncthreads();

  // ---- phase 1: bucketed counting on the subset (branch-free) ----
  for (int j = 0; j < SUB; j += 4) {
    #pragma unroll
    for (int t = 0; t < 4; ++t) {
      float4 p = seg[j + t];
      float inner = fmaf(p.x, me.x, fmaf(p.y, me.y, p.z * me.z));
      float d  = fmaf(-2.0f, inner, me.w + p.w);
      float dc = __builtin_amdgcn_fmed3f(d, CLO, CHI);
      atomicAdd(hrow0 + ((__float_as_uint(dc) >> 21) << 6), 1u);
    }
  }
  __syncthreads();

  // ---- scan: crit = first bucket with subset-cum >= KK (each wave redundantly) ----
  unsigned cum = 0; int crit = 0;
  #pragma unroll 1
  for (int t = 0; t < NBUCK; ++t) {
    cum += hist[t * 64 + lane];
    crit += (cum < KK) ? 1 : 0;
  }
  const float Tup = __uint_as_float((unsigned)(BOFF + crit + 1) << 21);

  // ---- phase 2: collect candidates with raw d < Tup over the FULL segment ----
  const int mbase = wid * SEG;
  for (int j = 0; j < SEG; j += 8) {
    float d[8]; bool a[8];
    #pragma unroll
    for (int t = 0; t < 8; ++t) {
      float4 p = seg[j + t];
      float inner = fmaf(p.x, me.x, fmaf(p.y, me.y, p.z * me.z));
      d[t] = fmaf(-2.0f, inner, me.w + p.w);
      a[t] = d[t] < Tup;
    }
    if (__any(a[0] | a[1] | a[2] | a[3] | a[4] | a[5] | a[6] | a[7])) {
      #pragma unroll
      for (int t = 0; t < 8; ++t) {
        if (a[t]) {
          int bb = (int)__float_as_uint(d[t]);
          unsigned s = (unsigned)(bb ^ ((bb >> 31) | 0x80000000));   // float -> sortable uint
          unsigned c = atomicAdd(&ccnt[lane], 1u);
          if (c < CAP)
            cdk[c * 64 + lane] = ((unsigned long long)s << 32) | (unsigned)(mbase + j + t);
        }
      }
    }
  }
  __syncthreads();

  // ---- phase 3: wave 0 selects the 20 smallest keys per row (set semantics) ----
  if (wid != 0) return;
  unsigned cnt = ccnt[lane];
  unsigned long long q[KK];
  #pragma unroll
  for (int k = 0; k < KK; ++k) q[k] = ~0ULL;
  int C = (int)(cnt < CAP ? cnt : CAP);
  #pragma unroll 1
  for (int c = 0; c < C; ++c) {
    unsigned long long key = cdk[c * 64 + lane];
    if (key < q[KK - 1]) {
      #pragma unroll
      for (int k = 0; k < KK; ++k) {
        bool sw = key < q[k];
        unsigned long long tq = q[k];
        q[k] = sw ? key : tq;
        key  = sw ? tq : key;
      }
    }
  }
  // exec-masked exact fallback: undercount (clamp-edge pathology) or CAP overflow
  if (__any(cnt < KK || cnt > CAP)) {
    if (cnt < KK || cnt > CAP) {
      #pragma unroll
      for (int k = 0; k < KK; ++k) q[k] = ~0ULL;
      #pragma unroll 1
      for (int j = 0; j < Nn; ++j) {
        float4 p = Pb[j];
        float inner = fmaf(p.x, me.x, fmaf(p.y, me.y, p.z * me.z));
        float dd = fmaf(-2.0f, inner, me.w + p.w);
        int bb = (int)__float_as_uint(dd);
        unsigned s = (unsigned)(bb ^ ((bb >> 31) | 0x80000000));
        unsigned long long key = ((unsigned long long)s << 32) | (unsigned)j;
        if (key < q[KK - 1]) {
          #pragma unroll
          for (int k = 0; k < KK; ++k) {
            bool sw = key < q[k];
            unsigned long long tq = q[k];
            q[k] = sw ? key : tq;
            key  = sw ? tq : key;
          }
        }
      }
    }
  }
  int* op = idx_out + (b * Nn + n) * KK;
  #pragma unroll
  for (int k = 0; k < KK; ++k) op[k] = (int)(q[k] & 0xFFFFFFFFu);
}

// ---------------- gather v over neighbors: pm = u + max_k v ; accumulate S1,S2 --------------

__global__ __launch_bounds__(256) void gather_kernel(const int* __restrict__ idx,
                                                     float* __restrict__ u,      // in-place -> pm
                                                     const float* __restrict__ v,
                                                     float* __restrict__ stats) {
  __shared__ float ls1[4][64], ls2[4][64];
  int b  = blockIdx.y;
  int o  = threadIdx.x & 63;
  int ys = threadIdx.x >> 6;
  const float* vb = v + (size_t)b * Nn * OO;
  float s1 = 0.f, s2 = 0.f;
  for (int i = 0; i < 16; ++i) {
    int n = blockIdx.x * 64 + ys * 16 + i;
    const int* ip = idx + (b * Nn + n) * KK;
    float un = u[(size_t)(b * Nn + n) * OO + o];
    float sv = 0.f, sv2 = 0.f, mv = -__builtin_inff();
    #pragma unroll
    for (int k = 0; k < KK; ++k) {
      int j = ip[k];
      float val = vb[(size_t)j * OO + o];
      sv += val; sv2 += val * val; mv = fmaxf(mv, val);
    }
    u[(size_t)(b * Nn + n) * OO + o] = un + mv;
    s1 += (float)KK * un + sv;
    s2 += (float)KK * un * un + 2.f * un * sv + sv2;
  }
  ls1[ys][o] = s1; ls2[ys][o] = s2;
  __syncthreads();
  if (ys == 0) {
    float t1 = ls1[0][o] + ls1[1][o] + ls1[2][o] + ls1[3][o];
    float t2 = ls2[0][o] + ls2[1][o] + ls2[2][o] + ls2[3][o];
    atomicAdd(&stats[(b * OO + o) * 2 + 0], t1);
    atomicAdd(&stats[(b * OO + o) * 2 + 1], t2);
  }
}

// ---------------- finalize: normalize + lrelu + transpose to [b][o][n] ----------------------

__global__ __launch_bounds__(256) void out_kernel(const float* __restrict__ pm,
                                                  const float* __restrict__ stats,
                                                  float* __restrict__ out) {
  __shared__ float tile[64][65];
  int b  = blockIdx.y;
  int o  = threadIdx.x & 63;
  int ys = threadIdx.x >> 6;
  const float inv_cnt = 1.0f / (float)(Nn * KK);
  float S1 = stats[(b * OO + o) * 2 + 0];
  float S2 = stats[(b * OO + o) * 2 + 1];
  float mean = S1 * inv_cnt;
  float var  = S2 * inv_cnt - mean * mean;
  float istd = rsqrtf(var + EPSF);
  for (int i = 0; i < 16; ++i) {
    int n = blockIdx.x * 64 + ys * 16 + i;
    float val = (pm[(size_t)(b * Nn + n) * OO + o] - mean) * istd;
    val = (val >= 0.f) ? val : SLOPEF * val;
    tile[ys * 16 + i][o] = val;
  }
  __syncthreads();
  int nb = blockIdx.x * 64;
  for (int i = 0; i < 16; ++i) {
    int oo = ys * 16 + i;
    out[(size_t)(b * OO + oo) * Nn + nb + o] = tile[o][oo];
  }
}

// ---------------- launch ---------------------------------------------------------------------

extern "C" void kernel_launch(void* const* d_in, const int* in_sizes, int n_in,
                              void* d_out, int out_size, void* d_ws, size_t ws_size,
                              hipStream_t stream) {
  const float* x = (const float*)d_in[0];
  const float* W = (const float*)d_in[1];
  float* out = (float*)d_out;

  char* ws = (char*)d_ws;
  int*    idx   = (int*)ws;                                     // 2,621,440 B
  float*  u     = (float*)(ws + 2621440);                       // 8,388,608 B (becomes pm)
  float*  v     = (float*)(ws + 2621440 + 8388608);             // 8,388,608 B
  float*  stats = (float*)(ws + 2621440 + 2 * 8388608);         // 2,048 B
  float4* P     = (float4*)(ws + 2621440 + 2 * 8388608 + 4096); // 524,288 B

  hipMemsetAsync(stats, 0, Bb * OO * 2 * sizeof(float), stream);
  uv_kernel    <<<dim3((Bb * Nn * OO) / 256), 256, 0, stream>>>(x, W, u, v, P);
  knn_kernel   <<<dim3(128, Bb), 1024, 0, stream>>>(P, idx);
  gather_kernel<<<dim3(128, Bb), 256, 0, stream>>>(idx, u, v, stats);
  out_kernel   <<<dim3(128, Bb), 256, 0, stream>>>(u, stats, out);
}